// Round 6
// baseline (240.383 us; speedup 1.0000x reference)
//
#include <hip/hip_runtime.h>
#include <hip/hip_bf16.h>

// Fused self-attention block: LN -> QKV -> MHA(16 heads, dh=64) -> WO -> +x
// B=4, S=1024, HIDDEN=1024. All inputs fp32; big GEMMs run bf16 MFMA w/ fp32 accum.
//
// R6: isolate R5's flash regression. Flash reverted to the R4 structure (62 µs
// proven: dbuf, one vmcnt(0)+s_barrier per tile, grid (16,16,4), no unroll-2,
// no defer-max branch, no XCD swizzle) keeping ONLY two pure instruction
// substitutions from R5: exp2-domain softmax + v_cvt_pk_bf16_f32 P-pack.
// gemm keeps R5's 3-buffer counted-vmcnt pipeline (helped ~5 µs).
//
// Workspace layout (48 MiB total):
//   [ 0,  8M)  normed   bf16 [4096][1024]
//   [ 8, 16M)  wcat     bf16 [wq;wk;wv;wo] = [4096][1024]
//   [16, 24M)  Qg       bf16 [B,H,S,64]  (pre-scaled by log2e/sqrt(64))
//   [24, 32M)  Kg       bf16 [B,H,S,64]
//   [32, 40M)  Vt       bf16 [B,H,64,S]
//   [40, 48M)  ctx      bf16 [4096][1024]  ([B,S,H,dh] flattened)

typedef unsigned short u16;
typedef __attribute__((ext_vector_type(8))) short short8;
typedef __attribute__((ext_vector_type(4))) float f32x4;

__device__ __forceinline__ u16 f2bf(float f) {
  union { float f; unsigned u; } cv; cv.f = f;
  unsigned u = cv.u + 0x7fffu + ((cv.u >> 16) & 1u);   // RNE
  return (u16)(u >> 16);
}

__device__ __forceinline__ unsigned pk_bf16(float lo, float hi) {
  unsigned r;
  asm("v_cvt_pk_bf16_f32 %0, %1, %2" : "=v"(r) : "v"(lo), "v"(hi));
  return r;
}

__device__ __forceinline__ void gload_lds16(const void* g, void* l) {
  __builtin_amdgcn_global_load_lds(
      (const __attribute__((address_space(1))) void*)g,
      (__attribute__((address_space(3))) void*)l, 16, 0, 0);
}

__device__ __forceinline__ f32x4 mfma16(short8 a, short8 b, f32x4 c) {
  return __builtin_amdgcn_mfma_f32_16x16x32_bf16(a, b, c, 0, 0, 0);
}

// ---------------- LayerNorm: fp32 in -> bf16 normed ----------------
__global__ __launch_bounds__(256) void ln_kernel(const float* __restrict__ x,
                                                 const float* __restrict__ gamma,
                                                 const float* __restrict__ beta,
                                                 u16* __restrict__ outn) {
  __shared__ float sm[4];
  const int row = blockIdx.x, t = threadIdx.x;
  float4 v = ((const float4*)(x + (size_t)row * 1024))[t];
  float s = v.x + v.y + v.z + v.w;
#pragma unroll
  for (int off = 32; off; off >>= 1) s += __shfl_down(s, off);
  if ((t & 63) == 0) sm[t >> 6] = s;
  __syncthreads();
  const float mu = (sm[0] + sm[1] + sm[2] + sm[3]) * (1.0f / 1024.0f);
  const float dx = v.x - mu, dy = v.y - mu, dz = v.z - mu, dw = v.w - mu;
  float vs = dx * dx + dy * dy + dz * dz + dw * dw;
  __syncthreads();
#pragma unroll
  for (int off = 32; off; off >>= 1) vs += __shfl_down(vs, off);
  if ((t & 63) == 0) sm[t >> 6] = vs;
  __syncthreads();
  const float var = (sm[0] + sm[1] + sm[2] + sm[3]) * (1.0f / 1024.0f);
  const float rstd = rsqrtf(var + 1e-5f);
  float4 g = ((const float4*)gamma)[t];
  float4 b = ((const float4*)beta)[t];
  uint2 pk;
  pk.x = (unsigned)f2bf(dx * rstd * g.x + b.x) | ((unsigned)f2bf(dy * rstd * g.y + b.y) << 16);
  pk.y = (unsigned)f2bf(dz * rstd * g.z + b.z) | ((unsigned)f2bf(dw * rstd * g.w + b.w) << 16);
  *(uint2*)&outn[(size_t)row * 1024 + t * 4] = pk;
}

// ---------------- weight convert fp32 -> bf16, concat [wq;wk;wv;wo] ----------------
__global__ __launch_bounds__(256) void cvt_w(const float* __restrict__ wq,
                                             const float* __restrict__ wk,
                                             const float* __restrict__ wv,
                                             const float* __restrict__ wo,
                                             u16* __restrict__ out) {
  const int i = blockIdx.x * 256 + threadIdx.x;
  const int e = i * 4;
  const int seg = e >> 20;
  const int off = e & 1048575;
  const float* src = (seg == 0) ? wq : (seg == 1) ? wk : (seg == 2) ? wv : wo;
  float4 v = *(const float4*)(src + off);
  uint2 pk;
  pk.x = (unsigned)f2bf(v.x) | ((unsigned)f2bf(v.y) << 16);
  pk.y = (unsigned)f2bf(v.z) | ((unsigned)f2bf(v.w) << 16);
  *(uint2*)&out[e] = pk;
}

// ---------------- bt-GEMM: C[M,N] = A[M,K] * Bt[N,K]^T  (K=1024) ----------------
// BK=32, 3-buffer 2-ahead pipeline, counted vmcnt, XOR-swizzled tiles.
// MODE 0: BM=128, N=3072; epilogue via LDS -> packed 16B stores to
//         Qg(*log2e/8)/Kg [B,H,S,64] and transposed Vt [B,H,64,S].
// MODE 1: BM=64, N=1024; fp32 out + residual (direct stores).
template <int MODE>
__global__ __launch_bounds__(256) void gemm_bt(const u16* __restrict__ A,
                                               const u16* __restrict__ Bm,
                                               u16* __restrict__ outQ, u16* __restrict__ outK,
                                               u16* __restrict__ outVt,
                                               float* __restrict__ outF,
                                               const float* __restrict__ resid) {
  constexpr int BM = (MODE == 0) ? 128 : 64;
  constexpr int MI = BM / 32;
  constexpr int ASZ = BM * 32;                 // u16 per A buffer
  constexpr int BSZ = 128 * 32;                // u16 per B buffer
  __shared__ u16 sm[3 * (ASZ + BSZ)];

  const int m0 = blockIdx.y * BM, n0 = blockIdx.x * 128;
  const int t = threadIdx.x;
  const int wid = t >> 6, lane = t & 63;
  const int wm = (wid >> 1) * (BM / 2), wn = (wid & 1) * 64;
  const int lr = lane & 15, lg = lane >> 4;
  const int swz = (lg ^ ((lr >> 1) & 3)) << 3;
  f32x4 acc[MI][4] = {};

  const int scol = (((t & 3) ^ ((t >> 3) & 3)) << 3);
  const u16* aT = A + (size_t)(m0 + (t >> 2)) * 1024 + scol;
  const u16* bT = Bm + (size_t)(n0 + (t >> 2)) * 1024 + scol;

  auto STAGE = [&](int buf, int kt) {
    const int k0 = kt * 32;
#pragma unroll
    for (int cc = 0; cc < BM / 64; cc++)
      gload_lds16(aT + (size_t)cc * 65536 + k0, &sm[buf * ASZ + cc * 2048 + t * 8]);
#pragma unroll
    for (int cc = 0; cc < 2; cc++)
      gload_lds16(bT + (size_t)cc * 65536 + k0, &sm[3 * ASZ + buf * BSZ + cc * 2048 + t * 8]);
  };

  STAGE(0, 0);
  STAGE(1, 1);

  int cb = 0, sb = 2;
  for (int kt = 0; kt < 32; kt++) {
    if constexpr (MODE == 0)
      asm volatile("s_waitcnt vmcnt(4)" ::: "memory");
    else
      asm volatile("s_waitcnt vmcnt(3)" ::: "memory");
    __builtin_amdgcn_s_barrier();
    __builtin_amdgcn_sched_barrier(0);

    STAGE(sb, (kt + 2) & 31);   // wrap: last 2 iters restage t0/t1 (never read)

    short8 af[MI], bfr[4];
#pragma unroll
    for (int mi = 0; mi < MI; mi++)
      af[mi] = *(const short8*)&sm[cb * ASZ + (wm + mi * 16 + lr) * 32 + swz];
#pragma unroll
    for (int ni = 0; ni < 4; ni++)
      bfr[ni] = *(const short8*)&sm[3 * ASZ + cb * BSZ + (wn + ni * 16 + lr) * 32 + swz];
    __builtin_amdgcn_s_setprio(1);
#pragma unroll
    for (int mi = 0; mi < MI; mi++)
#pragma unroll
      for (int ni = 0; ni < 4; ni++)
        acc[mi][ni] = mfma16(af[mi], bfr[ni], acc[mi][ni]);
    __builtin_amdgcn_s_setprio(0);

    cb = (cb == 2) ? 0 : cb + 1;
    sb = (sb == 2) ? 0 : sb + 1;
  }

  if (MODE == 1) {
#pragma unroll
    for (int mi = 0; mi < MI; mi++)
#pragma unroll
      for (int ni = 0; ni < 4; ni++)
#pragma unroll
        for (int r = 0; r < 4; r++) {
          const int i = m0 + wm + mi * 16 + lg * 4 + r;
          const int j = n0 + wn + ni * 16 + lr;
          const size_t o = (size_t)i * 1024 + j;
          outF[o] = acc[mi][ni][r] + resid[o];
        }
    return;
  }

  // ---- MODE 0 epilogue: drain in-flight wrap stages, then reuse LDS ----
  asm volatile("s_waitcnt vmcnt(0)" ::: "memory");
  __syncthreads();

  const int seg = (n0 + wn) >> 10;
  const int g8 = lane >> 3, j8 = lane & 7;
  if (seg < 2) {
    u16* epi = &sm[wid * 4608];
    // Q gets log2e/8 so flash can use exp2 directly (fp32 mul before bf16 round)
    const float qs = (seg == 0) ? 0.18033688f : 1.0f;
#pragma unroll
    for (int mi = 0; mi < 4; mi++)
#pragma unroll
      for (int ni = 0; ni < 4; ni++)
#pragma unroll
        for (int r = 0; r < 4; r++)
          epi[(mi * 16 + lg * 4 + r) * 72 + ni * 16 + lr] = f2bf(acc[mi][ni][r] * qs);
    __syncthreads();
    u16* dst = (seg == 0) ? outQ : outK;
    const int h = ((n0 + wn) & 1023) >> 6;
#pragma unroll
    for (int it = 0; it < 8; it++) {
      const int ml = it * 8 + g8;
      short8 v = *(const short8*)&epi[ml * 72 + j8 * 8];
      const int i = m0 + wm + ml;
      const int b = i >> 10, s_ = i & 1023;
      *(short8*)&dst[((size_t)(b * 16 + h) * 1024 + s_) * 64 + j8 * 8] = v;
    }
  } else {
    u16* epi = &sm[wid * 4096];
#pragma unroll
    for (int mi = 0; mi < 4; mi++)
#pragma unroll
      for (int ni = 0; ni < 4; ni++) {
        const int n = ni * 16 + lr;
        const int c2 = 4 * mi + lg;
        uint2 w;
        w.x = pk_bf16(acc[mi][ni][0], acc[mi][ni][1]);
        w.y = pk_bf16(acc[mi][ni][2], acc[mi][ni][3]);
        *(uint2*)&epi[n * 64 + ((c2 ^ (n & 15)) << 2)] = w;
      }
    __syncthreads();
    const int h = ((n0 + wn) & 1023) >> 6;
    const int b = (m0 + wm) >> 10, sbm = (m0 + wm) & 1023;
#pragma unroll
    for (int it = 0; it < 8; it++) {
      const int n = it * 8 + g8;
      uint2 w0 = *(const uint2*)&epi[n * 64 + (((2 * j8) ^ (n & 15)) << 2)];
      uint2 w1 = *(const uint2*)&epi[n * 64 + (((2 * j8 + 1) ^ (n & 15)) << 2)];
      uint4 w; w.x = w0.x; w.y = w0.y; w.z = w1.x; w.w = w1.y;
      *(uint4*)&outVt[((size_t)(b * 16 + h) * 64 + n) * 1024 + sbm + j8 * 8] = w;
    }
  }
}

// ---------------- flash attention: R4 structure + {exp2 domain, cvt_pk} only ----
// SWAPPED QK^T: s = mfma(K, Q) -> rows = keys, cols = q (lane owns q = qbase+lr).
// K/V LDS chunk-XOR swizzled; dbuf with one vmcnt(0)+s_barrier per tile; mask
// read directly as float4 (fragment-aligned in swapped layout), prefetched.
__global__ __launch_bounds__(256) void flash_kernel(const u16* __restrict__ Qg,
                                                    const u16* __restrict__ Kg,
                                                    const u16* __restrict__ Vt,
                                                    const float* __restrict__ mask,
                                                    u16* __restrict__ ctx) {
  const int h = blockIdx.x, qt = blockIdx.y, b = blockIdx.z;
  const int bh = b * 16 + h;
  __shared__ u16 Ks[2][4096];       // dbuf swizzled [key][d]
  __shared__ u16 Vs[2][4096];       // dbuf swizzled [d][key]
  __shared__ u16 Ps[4][1024];       // per-wave swizzled P [16 q][64 key]
  const int t = threadIdx.x, wid = t >> 6, lane = t & 63;
  const int lr = lane & 15, lg = lane >> 4;
  const int hR = lr & 7;
  const int qbase = qt * 64 + wid * 16;

  short8 qf0, qf1;
  {
    const u16* qrow = Qg + ((size_t)bh * 1024 + qbase + lr) * 64;
    qf0 = *(const short8*)(qrow + lg * 8);
    qf1 = *(const short8*)(qrow + 32 + lg * 8);
  }
  f32x4 octx[4] = {};
  float m_ln = -1e30f, l_ln = 0.0f;   // log2-domain online softmax state (q = qbase+lr)

  const u16* kS0 = Kg + (size_t)bh * 65536;
  const u16* vS0 = Vt + (size_t)bh * 65536;
  const int srow = t >> 3, scb = t & 7;

  const float* mptr = mask + ((size_t)b * 1024 + qbase + lr) * 1024 + lg * 4;

  auto STAGE = [&](int nb, int kt) {
#pragma unroll
    for (int c = 0; c < 2; c++) {
      const int row = c * 32 + srow;
      const int sc = (scb ^ (row & 7)) * 8;
      gload_lds16(kS0 + (size_t)(kt * 64 + row) * 64 + sc, &Ks[nb][c * 2048 + t * 8]);
      gload_lds16(vS0 + (size_t)row * 1024 + kt * 64 + sc, &Vs[nb][c * 2048 + t * 8]);
    }
  };

  STAGE(0, 0);
  float mc[4][4];
#pragma unroll
  for (int kn = 0; kn < 4; kn++) {
    float4 v = *(const float4*)(mptr + kn * 16);
    mc[kn][0] = v.x; mc[kn][1] = v.y; mc[kn][2] = v.z; mc[kn][3] = v.w;
  }
  asm volatile("s_waitcnt vmcnt(0)" ::: "memory");
  __builtin_amdgcn_s_barrier();
  __builtin_amdgcn_sched_barrier(0);

  int cur = 0;
  for (int kt = 0; kt < 16; kt++) {
    const int ktn = (kt < 15) ? kt + 1 : 15;
    STAGE(cur ^ 1, ktn);
    float mnx[4][4];
#pragma unroll
    for (int kn = 0; kn < 4; kn++) {
      float4 v = *(const float4*)(mptr + ktn * 64 + kn * 16);
      mnx[kn][0] = v.x; mnx[kn][1] = v.y; mnx[kn][2] = v.z; mnx[kn][3] = v.w;
    }

    // ---- S(log2) = K Q^T + 14427*(mask-1): sv[kn][r] = score(key kn*16+lg*4+r, q=lr)
    float sv[4][4];
#pragma unroll
    for (int kn = 0; kn < 4; kn++) {
      const int R = kn * 16 + lr;
      short8 kf0 = *(const short8*)&Ks[cur][R * 64 + ((lg ^ hR) << 3)];
      short8 kf1 = *(const short8*)&Ks[cur][R * 64 + (((lg + 4) ^ hR) << 3)];
      f32x4 s = {};
      s = mfma16(kf0, qf0, s);
      s = mfma16(kf1, qf1, s);
#pragma unroll
      for (int r = 0; r < 4; r++)
        sv[kn][r] = s[r] + fmaf(14426.9504f, mc[kn][r], -14426.9504f);
    }

    // ---- online softmax for q=lr: in-register tree + 2 shfl_xor (unconditional)
    float mx0 = fmaxf(fmaxf(sv[0][0], sv[0][1]), fmaxf(sv[0][2], sv[0][3]));
    float mx1 = fmaxf(fmaxf(sv[1][0], sv[1][1]), fmaxf(sv[1][2], sv[1][3]));
    float mx2 = fmaxf(fmaxf(sv[2][0], sv[2][1]), fmaxf(sv[2][2], sv[2][3]));
    float mx3 = fmaxf(fmaxf(sv[3][0], sv[3][1]), fmaxf(sv[3][2], sv[3][3]));
    float mt = fmaxf(fmaxf(mx0, mx1), fmaxf(mx2, mx3));
    mt = fmaxf(mt, __shfl_xor(mt, 16));
    mt = fmaxf(mt, __shfl_xor(mt, 32));
    const float mn = fmaxf(m_ln, mt);
    const float f = exp2f(m_ln - mn);
    m_ln = mn;
    float ps = 0.0f;
#pragma unroll
    for (int kn = 0; kn < 4; kn++) {
      float p0 = exp2f(sv[kn][0] - mn), p1 = exp2f(sv[kn][1] - mn);
      float p2 = exp2f(sv[kn][2] - mn), p3 = exp2f(sv[kn][3] - mn);
      sv[kn][0] = p0; sv[kn][1] = p1; sv[kn][2] = p2; sv[kn][3] = p3;
      ps += (p0 + p1) + (p2 + p3);
    }
    ps += __shfl_xor(ps, 16);
    ps += __shfl_xor(ps, 32);
    l_ln = l_ln * f + ps;

    float fb[4];
#pragma unroll
    for (int r = 0; r < 4; r++)
      fb[r] = __shfl(f, (lane & 48) | (lg * 4 + r), 64);
#pragma unroll
    for (int g = 0; g < 4; g++)
#pragma unroll
      for (int r = 0; r < 4; r++) octx[g][r] *= fb[r];

    // ---- P -> per-wave swizzled LDS -> A-frags (cvt_pk pack)
    const int pswz = (lr & 7) << 1;
#pragma unroll
    for (int kn = 0; kn < 4; kn++) {
      uint2 w;
      w.x = pk_bf16(sv[kn][0], sv[kn][1]);
      w.y = pk_bf16(sv[kn][2], sv[kn][3]);
      *(uint2*)&Ps[wid][lr * 64 + (((kn * 4 + lg) ^ pswz) << 2)] = w;
    }
    short8 pa0 = *(const short8*)&Ps[wid][lr * 64 + (((2 * lg) ^ pswz) << 2)];
    short8 pa1 = *(const short8*)&Ps[wid][lr * 64 + (((8 + 2 * lg) ^ pswz) << 2)];

    // ---- PV
    __builtin_amdgcn_s_setprio(1);
#pragma unroll
    for (int g = 0; g < 4; g++) {
      const int R = g * 16 + lr;
      short8 vf0 = *(const short8*)&Vs[cur][R * 64 + ((lg ^ hR) << 3)];
      short8 vf1 = *(const short8*)&Vs[cur][R * 64 + (((lg + 4) ^ hR) << 3)];
      octx[g] = mfma16(pa0, vf0, octx[g]);
      octx[g] = mfma16(pa1, vf1, octx[g]);
    }
    __builtin_amdgcn_s_setprio(0);

    asm volatile("s_waitcnt vmcnt(0)" ::: "memory");
    __builtin_amdgcn_s_barrier();
    __builtin_amdgcn_sched_barrier(0);
    cur ^= 1;
#pragma unroll
    for (int kn = 0; kn < 4; kn++)
#pragma unroll
      for (int r = 0; r < 4; r++) mc[kn][r] = mnx[kn][r];
  }

  float lb[4];
#pragma unroll
  for (int r = 0; r < 4; r++)
    lb[r] = __shfl(l_ln, (lane & 48) | (lg * 4 + r), 64);
#pragma unroll
  for (int g = 0; g < 4; g++)
#pragma unroll
    for (int r = 0; r < 4; r++) {
      const int qr = qbase + lg * 4 + r;
      ctx[((size_t)b * 1024 + qr) * 1024 + h * 64 + g * 16 + lr] = f2bf(octx[g][r] / lb[r]);
    }
}

extern "C" void kernel_launch(void* const* d_in, const int* in_sizes, int n_in,
                              void* d_out, int out_size, void* d_ws, size_t ws_size,
                              hipStream_t stream) {
  const float* x     = (const float*)d_in[0];
  const float* mask  = (const float*)d_in[2];
  const float* wq    = (const float*)d_in[3];
  const float* wk    = (const float*)d_in[4];
  const float* wv    = (const float*)d_in[5];
  const float* wo    = (const float*)d_in[6];
  const float* gamma = (const float*)d_in[7];
  const float* beta  = (const float*)d_in[8];
  float* out = (float*)d_out;

  char* ws = (char*)d_ws;
  u16* normed = (u16*)(ws);
  u16* wcat   = (u16*)(ws + (8ull << 20));
  u16* Qg     = (u16*)(ws + (16ull << 20));
  u16* Kg     = (u16*)(ws + (24ull << 20));
  u16* Vtg    = (u16*)(ws + (32ull << 20));
  u16* ctx    = (u16*)(ws + (40ull << 20));
  u16* wo_bf  = wcat + 3072ull * 1024;

  ln_kernel<<<4096, 256, 0, stream>>>(x, gamma, beta, normed);
  cvt_w<<<4096, 256, 0, stream>>>(wq, wk, wv, wo, wcat);
  // QKV: M=4096, N=3072, 128x128 tiles
  gemm_bt<0><<<dim3(24, 32), 256, 0, stream>>>(normed, wcat, Qg, Kg, Vtg, nullptr, nullptr);
  // attention: grid x=h (16 heads share per-b mask slice in L2), y=qtile, z=b
  flash_kernel<<<dim3(16, 16, 4), 256, 0, stream>>>(Qg, Kg, Vtg, mask, ctx);
  // WO + residual: M=4096, N=1024, 64x128 tiles
  gemm_bt<1><<<dim3(8, 64), 256, 0, stream>>>(ctx, wo_bf, nullptr, nullptr, nullptr, out, x);
}

// Round 7
// 219.957 us; speedup vs baseline: 1.0929x; 1.0929x over previous
//
#include <hip/hip_runtime.h>
#include <hip/hip_bf16.h>

// Fused self-attention block: LN -> QKV -> MHA(16 heads, dh=64) -> WO -> +x
// B=4, S=1024, HIDDEN=1024. All inputs fp32; big GEMMs run bf16 MFMA w/ fp32 accum.
//
// R7: flash reverted byte-exact to the R4 kernel (62 µs proven). R5/R6's
// exp2f + inline-asm v_cvt_pk_bf16_f32 were the regression (guide m240:
// hand-written cvt_pk asm is -37% — scheduler-pinning; exp2f may take the
// accurate libm path). gemm keeps the R5 3-buffer counted-vmcnt pipeline;
// Q scale back to 0.125 (flash uses __expf).
//
// Workspace layout (48 MiB total):
//   [ 0,  8M)  normed   bf16 [4096][1024]
//   [ 8, 16M)  wcat     bf16 [wq;wk;wv;wo] = [4096][1024]
//   [16, 24M)  Qg       bf16 [B,H,S,64]  (pre-scaled by 1/sqrt(64))
//   [24, 32M)  Kg       bf16 [B,H,S,64]
//   [32, 40M)  Vt       bf16 [B,H,64,S]
//   [40, 48M)  ctx      bf16 [4096][1024]  ([B,S,H,dh] flattened)

typedef unsigned short u16;
typedef __attribute__((ext_vector_type(8))) short short8;
typedef __attribute__((ext_vector_type(4))) float f32x4;

__device__ __forceinline__ u16 f2bf(float f) {
  union { float f; unsigned u; } cv; cv.f = f;
  unsigned u = cv.u + 0x7fffu + ((cv.u >> 16) & 1u);   // RNE
  return (u16)(u >> 16);
}

__device__ __forceinline__ void gload_lds16(const void* g, void* l) {
  __builtin_amdgcn_global_load_lds(
      (const __attribute__((address_space(1))) void*)g,
      (__attribute__((address_space(3))) void*)l, 16, 0, 0);
}

__device__ __forceinline__ f32x4 mfma16(short8 a, short8 b, f32x4 c) {
  return __builtin_amdgcn_mfma_f32_16x16x32_bf16(a, b, c, 0, 0, 0);
}

// ---------------- LayerNorm: fp32 in -> bf16 normed ----------------
__global__ __launch_bounds__(256) void ln_kernel(const float* __restrict__ x,
                                                 const float* __restrict__ gamma,
                                                 const float* __restrict__ beta,
                                                 u16* __restrict__ outn) {
  __shared__ float sm[4];
  const int row = blockIdx.x, t = threadIdx.x;
  float4 v = ((const float4*)(x + (size_t)row * 1024))[t];
  float s = v.x + v.y + v.z + v.w;
#pragma unroll
  for (int off = 32; off; off >>= 1) s += __shfl_down(s, off);
  if ((t & 63) == 0) sm[t >> 6] = s;
  __syncthreads();
  const float mu = (sm[0] + sm[1] + sm[2] + sm[3]) * (1.0f / 1024.0f);
  const float dx = v.x - mu, dy = v.y - mu, dz = v.z - mu, dw = v.w - mu;
  float vs = dx * dx + dy * dy + dz * dz + dw * dw;
  __syncthreads();
#pragma unroll
  for (int off = 32; off; off >>= 1) vs += __shfl_down(vs, off);
  if ((t & 63) == 0) sm[t >> 6] = vs;
  __syncthreads();
  const float var = (sm[0] + sm[1] + sm[2] + sm[3]) * (1.0f / 1024.0f);
  const float rstd = rsqrtf(var + 1e-5f);
  float4 g = ((const float4*)gamma)[t];
  float4 b = ((const float4*)beta)[t];
  uint2 pk;
  pk.x = (unsigned)f2bf(dx * rstd * g.x + b.x) | ((unsigned)f2bf(dy * rstd * g.y + b.y) << 16);
  pk.y = (unsigned)f2bf(dz * rstd * g.z + b.z) | ((unsigned)f2bf(dw * rstd * g.w + b.w) << 16);
  *(uint2*)&outn[(size_t)row * 1024 + t * 4] = pk;
}

// ---------------- weight convert fp32 -> bf16, concat [wq;wk;wv;wo] ----------------
__global__ __launch_bounds__(256) void cvt_w(const float* __restrict__ wq,
                                             const float* __restrict__ wk,
                                             const float* __restrict__ wv,
                                             const float* __restrict__ wo,
                                             u16* __restrict__ out) {
  const int i = blockIdx.x * 256 + threadIdx.x;
  const int e = i * 4;
  const int seg = e >> 20;
  const int off = e & 1048575;
  const float* src = (seg == 0) ? wq : (seg == 1) ? wk : (seg == 2) ? wv : wo;
  float4 v = *(const float4*)(src + off);
  uint2 pk;
  pk.x = (unsigned)f2bf(v.x) | ((unsigned)f2bf(v.y) << 16);
  pk.y = (unsigned)f2bf(v.z) | ((unsigned)f2bf(v.w) << 16);
  *(uint2*)&out[e] = pk;
}

// ---------------- bt-GEMM: C[M,N] = A[M,K] * Bt[N,K]^T  (K=1024) ----------------
// BK=32, 3-buffer 2-ahead pipeline, counted vmcnt, XOR-swizzled tiles.
// MODE 0: BM=128, N=3072; epilogue via LDS -> packed 16B stores to
//         Qg(*0.125)/Kg [B,H,S,64] and transposed Vt [B,H,64,S].
// MODE 1: BM=64, N=1024; fp32 out + residual (direct stores).
template <int MODE>
__global__ __launch_bounds__(256) void gemm_bt(const u16* __restrict__ A,
                                               const u16* __restrict__ Bm,
                                               u16* __restrict__ outQ, u16* __restrict__ outK,
                                               u16* __restrict__ outVt,
                                               float* __restrict__ outF,
                                               const float* __restrict__ resid) {
  constexpr int BM = (MODE == 0) ? 128 : 64;
  constexpr int MI = BM / 32;
  constexpr int ASZ = BM * 32;                 // u16 per A buffer
  constexpr int BSZ = 128 * 32;                // u16 per B buffer
  __shared__ u16 sm[3 * (ASZ + BSZ)];

  const int m0 = blockIdx.y * BM, n0 = blockIdx.x * 128;
  const int t = threadIdx.x;
  const int wid = t >> 6, lane = t & 63;
  const int wm = (wid >> 1) * (BM / 2), wn = (wid & 1) * 64;
  const int lr = lane & 15, lg = lane >> 4;
  const int swz = (lg ^ ((lr >> 1) & 3)) << 3;
  f32x4 acc[MI][4] = {};

  const int scol = (((t & 3) ^ ((t >> 3) & 3)) << 3);
  const u16* aT = A + (size_t)(m0 + (t >> 2)) * 1024 + scol;
  const u16* bT = Bm + (size_t)(n0 + (t >> 2)) * 1024 + scol;

  auto STAGE = [&](int buf, int kt) {
    const int k0 = kt * 32;
#pragma unroll
    for (int cc = 0; cc < BM / 64; cc++)
      gload_lds16(aT + (size_t)cc * 65536 + k0, &sm[buf * ASZ + cc * 2048 + t * 8]);
#pragma unroll
    for (int cc = 0; cc < 2; cc++)
      gload_lds16(bT + (size_t)cc * 65536 + k0, &sm[3 * ASZ + buf * BSZ + cc * 2048 + t * 8]);
  };

  STAGE(0, 0);
  STAGE(1, 1);

  int cb = 0, sb = 2;
  for (int kt = 0; kt < 32; kt++) {
    if constexpr (MODE == 0)
      asm volatile("s_waitcnt vmcnt(4)" ::: "memory");
    else
      asm volatile("s_waitcnt vmcnt(3)" ::: "memory");
    __builtin_amdgcn_s_barrier();
    __builtin_amdgcn_sched_barrier(0);

    STAGE(sb, (kt + 2) & 31);   // wrap: last 2 iters restage t0/t1 (never read)

    short8 af[MI], bfr[4];
#pragma unroll
    for (int mi = 0; mi < MI; mi++)
      af[mi] = *(const short8*)&sm[cb * ASZ + (wm + mi * 16 + lr) * 32 + swz];
#pragma unroll
    for (int ni = 0; ni < 4; ni++)
      bfr[ni] = *(const short8*)&sm[3 * ASZ + cb * BSZ + (wn + ni * 16 + lr) * 32 + swz];
    __builtin_amdgcn_s_setprio(1);
#pragma unroll
    for (int mi = 0; mi < MI; mi++)
#pragma unroll
      for (int ni = 0; ni < 4; ni++)
        acc[mi][ni] = mfma16(af[mi], bfr[ni], acc[mi][ni]);
    __builtin_amdgcn_s_setprio(0);

    cb = (cb == 2) ? 0 : cb + 1;
    sb = (sb == 2) ? 0 : sb + 1;
  }

  if (MODE == 1) {
#pragma unroll
    for (int mi = 0; mi < MI; mi++)
#pragma unroll
      for (int ni = 0; ni < 4; ni++)
#pragma unroll
        for (int r = 0; r < 4; r++) {
          const int i = m0 + wm + mi * 16 + lg * 4 + r;
          const int j = n0 + wn + ni * 16 + lr;
          const size_t o = (size_t)i * 1024 + j;
          outF[o] = acc[mi][ni][r] + resid[o];
        }
    return;
  }

  // ---- MODE 0 epilogue: drain in-flight wrap stages, then reuse LDS ----
  asm volatile("s_waitcnt vmcnt(0)" ::: "memory");
  __syncthreads();

  const int seg = (n0 + wn) >> 10;
  const int g8 = lane >> 3, j8 = lane & 7;
  if (seg < 2) {
    u16* epi = &sm[wid * 4608];
    const float qs = (seg == 0) ? 0.125f : 1.0f;
#pragma unroll
    for (int mi = 0; mi < 4; mi++)
#pragma unroll
      for (int ni = 0; ni < 4; ni++)
#pragma unroll
        for (int r = 0; r < 4; r++)
          epi[(mi * 16 + lg * 4 + r) * 72 + ni * 16 + lr] = f2bf(acc[mi][ni][r] * qs);
    __syncthreads();
    u16* dst = (seg == 0) ? outQ : outK;
    const int h = ((n0 + wn) & 1023) >> 6;
#pragma unroll
    for (int it = 0; it < 8; it++) {
      const int ml = it * 8 + g8;
      short8 v = *(const short8*)&epi[ml * 72 + j8 * 8];
      const int i = m0 + wm + ml;
      const int b = i >> 10, s_ = i & 1023;
      *(short8*)&dst[((size_t)(b * 16 + h) * 1024 + s_) * 64 + j8 * 8] = v;
    }
  } else {
    u16* epi = &sm[wid * 4096];
#pragma unroll
    for (int mi = 0; mi < 4; mi++)
#pragma unroll
      for (int ni = 0; ni < 4; ni++) {
        const int n = ni * 16 + lr;
        const int c2 = 4 * mi + lg;
        uint2 w;
        w.x = (unsigned)f2bf(acc[mi][ni][0]) | ((unsigned)f2bf(acc[mi][ni][1]) << 16);
        w.y = (unsigned)f2bf(acc[mi][ni][2]) | ((unsigned)f2bf(acc[mi][ni][3]) << 16);
        *(uint2*)&epi[n * 64 + ((c2 ^ (n & 15)) << 2)] = w;
      }
    __syncthreads();
    const int h = ((n0 + wn) & 1023) >> 6;
    const int b = (m0 + wm) >> 10, sbm = (m0 + wm) & 1023;
#pragma unroll
    for (int it = 0; it < 8; it++) {
      const int n = it * 8 + g8;
      uint2 w0 = *(const uint2*)&epi[n * 64 + (((2 * j8) ^ (n & 15)) << 2)];
      uint2 w1 = *(const uint2*)&epi[n * 64 + (((2 * j8 + 1) ^ (n & 15)) << 2)];
      uint4 w; w.x = w0.x; w.y = w0.y; w.z = w1.x; w.w = w1.y;
      *(uint4*)&outVt[((size_t)(b * 16 + h) * 64 + n) * 1024 + sbm + j8 * 8] = w;
    }
  }
}

// ---------------- flash attention: per (b,h,qtile=64) block, 4 waves x 16 q-rows ----
// BYTE-EXACT R4 kernel (62 µs proven). SWAPPED QK^T: s = mfma(K, Q) -> rows = keys,
// cols = q (lane owns q = qbase+lr). K/V LDS chunk-XOR swizzled; dbuf with one
// vmcnt(0)+s_barrier per tile; mask read directly as float4, prefetched.
__global__ __launch_bounds__(256) void flash_kernel(const u16* __restrict__ Qg,
                                                    const u16* __restrict__ Kg,
                                                    const u16* __restrict__ Vt,
                                                    const float* __restrict__ mask,
                                                    u16* __restrict__ ctx) {
  const int h = blockIdx.x, qt = blockIdx.y, b = blockIdx.z;
  const int bh = b * 16 + h;
  __shared__ u16 Ks[2][4096];       // dbuf swizzled [key][d]
  __shared__ u16 Vs[2][4096];       // dbuf swizzled [d][key]
  __shared__ u16 Ps[4][1024];       // per-wave swizzled P [16 q][64 key]
  const int t = threadIdx.x, wid = t >> 6, lane = t & 63;
  const int lr = lane & 15, lg = lane >> 4;
  const int hR = lr & 7;
  const int qbase = qt * 64 + wid * 16;

  short8 qf0, qf1;
  {
    const u16* qrow = Qg + ((size_t)bh * 1024 + qbase + lr) * 64;
    qf0 = *(const short8*)(qrow + lg * 8);
    qf1 = *(const short8*)(qrow + 32 + lg * 8);
  }
  f32x4 octx[4] = {};
  float m_ln = -1e30f, l_ln = 0.0f;

  const u16* kS0 = Kg + (size_t)bh * 65536;
  const u16* vS0 = Vt + (size_t)bh * 65536;
  const int srow = t >> 3, scb = t & 7;

  const float* mptr = mask + ((size_t)b * 1024 + qbase + lr) * 1024 + lg * 4;

  auto STAGE = [&](int nb, int kt) {
#pragma unroll
    for (int c = 0; c < 2; c++) {
      const int row = c * 32 + srow;
      const int sc = (scb ^ (row & 7)) * 8;
      gload_lds16(kS0 + (size_t)(kt * 64 + row) * 64 + sc, &Ks[nb][c * 2048 + t * 8]);
      gload_lds16(vS0 + (size_t)row * 1024 + kt * 64 + sc, &Vs[nb][c * 2048 + t * 8]);
    }
  };

  STAGE(0, 0);
  float mc[4][4];
#pragma unroll
  for (int kn = 0; kn < 4; kn++) {
    float4 v = *(const float4*)(mptr + kn * 16);
    mc[kn][0] = v.x; mc[kn][1] = v.y; mc[kn][2] = v.z; mc[kn][3] = v.w;
  }
  asm volatile("s_waitcnt vmcnt(0)" ::: "memory");
  __builtin_amdgcn_s_barrier();
  __builtin_amdgcn_sched_barrier(0);

  int cur = 0;
  for (int kt = 0; kt < 16; kt++) {
    const int ktn = (kt < 15) ? kt + 1 : 15;
    STAGE(cur ^ 1, ktn);
    float mnx[4][4];
#pragma unroll
    for (int kn = 0; kn < 4; kn++) {
      float4 v = *(const float4*)(mptr + ktn * 64 + kn * 16);
      mnx[kn][0] = v.x; mnx[kn][1] = v.y; mnx[kn][2] = v.z; mnx[kn][3] = v.w;
    }

    // ---- S = K Q^T: sv[kn][r] = score(key kn*16+lg*4+r, q=lr)
    float sv[4][4];
#pragma unroll
    for (int kn = 0; kn < 4; kn++) {
      const int R = kn * 16 + lr;
      short8 kf0 = *(const short8*)&Ks[cur][R * 64 + ((lg ^ hR) << 3)];
      short8 kf1 = *(const short8*)&Ks[cur][R * 64 + (((lg + 4) ^ hR) << 3)];
      f32x4 s = {};
      s = mfma16(kf0, qf0, s);
      s = mfma16(kf1, qf1, s);
      __builtin_amdgcn_s_setprio(0);
#pragma unroll
      for (int r = 0; r < 4; r++)
        sv[kn][r] = s[r] + fmaf(10000.f, mc[kn][r], -10000.f);
    }

    // ---- online softmax for q=lr: in-register tree + 2 shfl_xor
    float mx0 = fmaxf(fmaxf(sv[0][0], sv[0][1]), fmaxf(sv[0][2], sv[0][3]));
    float mx1 = fmaxf(fmaxf(sv[1][0], sv[1][1]), fmaxf(sv[1][2], sv[1][3]));
    float mx2 = fmaxf(fmaxf(sv[2][0], sv[2][1]), fmaxf(sv[2][2], sv[2][3]));
    float mx3 = fmaxf(fmaxf(sv[3][0], sv[3][1]), fmaxf(sv[3][2], sv[3][3]));
    float mt = fmaxf(fmaxf(mx0, mx1), fmaxf(mx2, mx3));
    mt = fmaxf(mt, __shfl_xor(mt, 16));
    mt = fmaxf(mt, __shfl_xor(mt, 32));
    const float mn = fmaxf(m_ln, mt);
    const float f = __expf(m_ln - mn);
    m_ln = mn;
    float ps = 0.0f;
#pragma unroll
    for (int kn = 0; kn < 4; kn++) {
      float p0 = __expf(sv[kn][0] - mn), p1 = __expf(sv[kn][1] - mn);
      float p2 = __expf(sv[kn][2] - mn), p3 = __expf(sv[kn][3] - mn);
      sv[kn][0] = p0; sv[kn][1] = p1; sv[kn][2] = p2; sv[kn][3] = p3;
      ps += (p0 + p1) + (p2 + p3);
    }
    ps += __shfl_xor(ps, 16);
    ps += __shfl_xor(ps, 32);
    l_ln = l_ln * f + ps;

    float fb[4];
#pragma unroll
    for (int r = 0; r < 4; r++)
      fb[r] = __shfl(f, (lane & 48) | (lg * 4 + r), 64);
#pragma unroll
    for (int g = 0; g < 4; g++)
#pragma unroll
      for (int r = 0; r < 4; r++) octx[g][r] *= fb[r];

    // ---- P -> per-wave swizzled LDS -> A-frags
    const int pswz = (lr & 7) << 1;
#pragma unroll
    for (int kn = 0; kn < 4; kn++) {
      uint2 w;
      w.x = (unsigned)f2bf(sv[kn][0]) | ((unsigned)f2bf(sv[kn][1]) << 16);
      w.y = (unsigned)f2bf(sv[kn][2]) | ((unsigned)f2bf(sv[kn][3]) << 16);
      *(uint2*)&Ps[wid][lr * 64 + (((kn * 4 + lg) ^ pswz) << 2)] = w;
    }
    short8 pa0 = *(const short8*)&Ps[wid][lr * 64 + (((2 * lg) ^ pswz) << 2)];
    short8 pa1 = *(const short8*)&Ps[wid][lr * 64 + (((8 + 2 * lg) ^ pswz) << 2)];

    // ---- PV
    __builtin_amdgcn_s_setprio(1);
#pragma unroll
    for (int g = 0; g < 4; g++) {
      const int R = g * 16 + lr;
      short8 vf0 = *(const short8*)&Vs[cur][R * 64 + ((lg ^ hR) << 3)];
      short8 vf1 = *(const short8*)&Vs[cur][R * 64 + (((lg + 4) ^ hR) << 3)];
      octx[g] = mfma16(pa0, vf0, octx[g]);
      octx[g] = mfma16(pa1, vf1, octx[g]);
    }
    __builtin_amdgcn_s_setprio(0);

    asm volatile("s_waitcnt vmcnt(0)" ::: "memory");
    __builtin_amdgcn_s_barrier();
    __builtin_amdgcn_sched_barrier(0);
    cur ^= 1;
#pragma unroll
    for (int kn = 0; kn < 4; kn++)
#pragma unroll
      for (int r = 0; r < 4; r++) mc[kn][r] = mnx[kn][r];
  }

  float lb[4];
#pragma unroll
  for (int r = 0; r < 4; r++)
    lb[r] = __shfl(l_ln, (lane & 48) | (lg * 4 + r), 64);
#pragma unroll
  for (int g = 0; g < 4; g++)
#pragma unroll
    for (int r = 0; r < 4; r++) {
      const int qr = qbase + lg * 4 + r;
      ctx[((size_t)b * 1024 + qr) * 1024 + h * 64 + g * 16 + lr] = f2bf(octx[g][r] / lb[r]);
    }
}

extern "C" void kernel_launch(void* const* d_in, const int* in_sizes, int n_in,
                              void* d_out, int out_size, void* d_ws, size_t ws_size,
                              hipStream_t stream) {
  const float* x     = (const float*)d_in[0];
  const float* mask  = (const float*)d_in[2];
  const float* wq    = (const float*)d_in[3];
  const float* wk    = (const float*)d_in[4];
  const float* wv    = (const float*)d_in[5];
  const float* wo    = (const float*)d_in[6];
  const float* gamma = (const float*)d_in[7];
  const float* beta  = (const float*)d_in[8];
  float* out = (float*)d_out;

  char* ws = (char*)d_ws;
  u16* normed = (u16*)(ws);
  u16* wcat   = (u16*)(ws + (8ull << 20));
  u16* Qg     = (u16*)(ws + (16ull << 20));
  u16* Kg     = (u16*)(ws + (24ull << 20));
  u16* Vtg    = (u16*)(ws + (32ull << 20));
  u16* ctx    = (u16*)(ws + (40ull << 20));
  u16* wo_bf  = wcat + 3072ull * 1024;

  ln_kernel<<<4096, 256, 0, stream>>>(x, gamma, beta, normed);
  cvt_w<<<4096, 256, 0, stream>>>(wq, wk, wv, wo, wcat);
  // QKV: M=4096, N=3072, 128x128 tiles
  gemm_bt<0><<<dim3(24, 32), 256, 0, stream>>>(normed, wcat, Qg, Kg, Vtg, nullptr, nullptr);
  // attention: grid x=h (16 heads share per-b mask slice in L2), y=qtile, z=b
  flash_kernel<<<dim3(16, 16, 4), 256, 0, stream>>>(Qg, Kg, Vtg, mask, ctx);
  // WO + residual: M=4096, N=1024, 64x128 tiles
  gemm_bt<1><<<dim3(8, 64), 256, 0, stream>>>(ctx, wo_bf, nullptr, nullptr, nullptr, out, x);
}

// Round 9
// 217.518 us; speedup vs baseline: 1.1051x; 1.0112x over previous
//
#include <hip/hip_runtime.h>
#include <hip/hip_bf16.h>

// Fused self-attention block: LN -> QKV -> MHA(16 heads, dh=64) -> WO -> +x
// B=4, S=1024, HIDDEN=1024. All inputs fp32; big GEMMs run bf16 MFMA w/ fp32 accum.
//
// R9 == R8 resubmitted verbatim (R8 bench died on container acquisition, kernel
// never ran). Changes vs R7:
//  - f2bf now uses __float2bfloat16 (RNE, same bits) -> compiler emits the
//    gfx950 HW bf16 convert instead of 4-op bit arithmetic. No inline asm.
//  - ln_kernel + cvt_w merged into one prep kernel (both BW-bound, independent;
//    overlap + one less launch).
//  - gemms/flash structure unchanged (R7-proven).
//
// Workspace layout (48 MiB total):
//   [ 0,  8M)  normed   bf16 [4096][1024]
//   [ 8, 16M)  wcat     bf16 [wq;wk;wv;wo] = [4096][1024]
//   [16, 24M)  Qg       bf16 [B,H,S,64]  (pre-scaled by 1/sqrt(64))
//   [24, 32M)  Kg       bf16 [B,H,S,64]
//   [32, 40M)  Vt       bf16 [B,H,64,S]
//   [40, 48M)  ctx      bf16 [4096][1024]  ([B,S,H,dh] flattened)

typedef unsigned short u16;
typedef __attribute__((ext_vector_type(8))) short short8;
typedef __attribute__((ext_vector_type(4))) float f32x4;

__device__ __forceinline__ u16 f2bf(float f) {
  __hip_bfloat16 h = __float2bfloat16(f);   // RNE; compiler emits HW cvt
  u16 u;
  __builtin_memcpy(&u, &h, 2);
  return u;
}

__device__ __forceinline__ void gload_lds16(const void* g, void* l) {
  __builtin_amdgcn_global_load_lds(
      (const __attribute__((address_space(1))) void*)g,
      (__attribute__((address_space(3))) void*)l, 16, 0, 0);
}

__device__ __forceinline__ f32x4 mfma16(short8 a, short8 b, f32x4 c) {
  return __builtin_amdgcn_mfma_f32_16x16x32_bf16(a, b, c, 0, 0, 0);
}

// ---------------- prep: LN (blocks 0..4095) + weight cvt (blocks 4096..8191) ----
__global__ __launch_bounds__(256) void prep_kernel(const float* __restrict__ x,
                                                   const float* __restrict__ gamma,
                                                   const float* __restrict__ beta,
                                                   u16* __restrict__ outn,
                                                   const float* __restrict__ wq,
                                                   const float* __restrict__ wk,
                                                   const float* __restrict__ wv,
                                                   const float* __restrict__ wo,
                                                   u16* __restrict__ outw) {
  const int t = threadIdx.x;
  if (blockIdx.x < 4096) {
    __shared__ float sm[4];
    const int row = blockIdx.x;
    float4 v = ((const float4*)(x + (size_t)row * 1024))[t];
    float s = v.x + v.y + v.z + v.w;
#pragma unroll
    for (int off = 32; off; off >>= 1) s += __shfl_down(s, off);
    if ((t & 63) == 0) sm[t >> 6] = s;
    __syncthreads();
    const float mu = (sm[0] + sm[1] + sm[2] + sm[3]) * (1.0f / 1024.0f);
    const float dx = v.x - mu, dy = v.y - mu, dz = v.z - mu, dw = v.w - mu;
    float vs = dx * dx + dy * dy + dz * dz + dw * dw;
    __syncthreads();
#pragma unroll
    for (int off = 32; off; off >>= 1) vs += __shfl_down(vs, off);
    if ((t & 63) == 0) sm[t >> 6] = vs;
    __syncthreads();
    const float var = (sm[0] + sm[1] + sm[2] + sm[3]) * (1.0f / 1024.0f);
    const float rstd = rsqrtf(var + 1e-5f);
    float4 g = ((const float4*)gamma)[t];
    float4 b = ((const float4*)beta)[t];
    uint2 pk;
    pk.x = (unsigned)f2bf(dx * rstd * g.x + b.x) | ((unsigned)f2bf(dy * rstd * g.y + b.y) << 16);
    pk.y = (unsigned)f2bf(dz * rstd * g.z + b.z) | ((unsigned)f2bf(dw * rstd * g.w + b.w) << 16);
    *(uint2*)&outn[(size_t)row * 1024 + t * 4] = pk;
  } else {
    const int i = (blockIdx.x - 4096) * 256 + t;
    const int e = i * 4;
    const int seg = e >> 20;
    const int off = e & 1048575;
    const float* src = (seg == 0) ? wq : (seg == 1) ? wk : (seg == 2) ? wv : wo;
    float4 v = *(const float4*)(src + off);
    uint2 pk;
    pk.x = (unsigned)f2bf(v.x) | ((unsigned)f2bf(v.y) << 16);
    pk.y = (unsigned)f2bf(v.z) | ((unsigned)f2bf(v.w) << 16);
    *(uint2*)&outw[e] = pk;
  }
}

// ---------------- bt-GEMM: C[M,N] = A[M,K] * Bt[N,K]^T  (K=1024) ----------------
// BK=32, 3-buffer 2-ahead pipeline, counted vmcnt, XOR-swizzled tiles.
// MODE 0: BM=128, N=3072; epilogue via LDS -> packed 16B stores to
//         Qg(*0.125)/Kg [B,H,S,64] and transposed Vt [B,H,64,S].
// MODE 1: BM=64, N=1024; fp32 out + residual (direct stores).
template <int MODE>
__global__ __launch_bounds__(256) void gemm_bt(const u16* __restrict__ A,
                                               const u16* __restrict__ Bm,
                                               u16* __restrict__ outQ, u16* __restrict__ outK,
                                               u16* __restrict__ outVt,
                                               float* __restrict__ outF,
                                               const float* __restrict__ resid) {
  constexpr int BM = (MODE == 0) ? 128 : 64;
  constexpr int MI = BM / 32;
  constexpr int ASZ = BM * 32;                 // u16 per A buffer
  constexpr int BSZ = 128 * 32;                // u16 per B buffer
  __shared__ u16 sm[3 * (ASZ + BSZ)];

  const int m0 = blockIdx.y * BM, n0 = blockIdx.x * 128;
  const int t = threadIdx.x;
  const int wid = t >> 6, lane = t & 63;
  const int wm = (wid >> 1) * (BM / 2), wn = (wid & 1) * 64;
  const int lr = lane & 15, lg = lane >> 4;
  const int swz = (lg ^ ((lr >> 1) & 3)) << 3;
  f32x4 acc[MI][4] = {};

  const int scol = (((t & 3) ^ ((t >> 3) & 3)) << 3);
  const u16* aT = A + (size_t)(m0 + (t >> 2)) * 1024 + scol;
  const u16* bT = Bm + (size_t)(n0 + (t >> 2)) * 1024 + scol;

  auto STAGE = [&](int buf, int kt) {
    const int k0 = kt * 32;
#pragma unroll
    for (int cc = 0; cc < BM / 64; cc++)
      gload_lds16(aT + (size_t)cc * 65536 + k0, &sm[buf * ASZ + cc * 2048 + t * 8]);
#pragma unroll
    for (int cc = 0; cc < 2; cc++)
      gload_lds16(bT + (size_t)cc * 65536 + k0, &sm[3 * ASZ + buf * BSZ + cc * 2048 + t * 8]);
  };

  STAGE(0, 0);
  STAGE(1, 1);

  int cb = 0, sb = 2;
  for (int kt = 0; kt < 32; kt++) {
    if constexpr (MODE == 0)
      asm volatile("s_waitcnt vmcnt(4)" ::: "memory");
    else
      asm volatile("s_waitcnt vmcnt(3)" ::: "memory");
    __builtin_amdgcn_s_barrier();
    __builtin_amdgcn_sched_barrier(0);

    STAGE(sb, (kt + 2) & 31);   // wrap: last 2 iters restage t0/t1 (never read)

    short8 af[MI], bfr[4];
#pragma unroll
    for (int mi = 0; mi < MI; mi++)
      af[mi] = *(const short8*)&sm[cb * ASZ + (wm + mi * 16 + lr) * 32 + swz];
#pragma unroll
    for (int ni = 0; ni < 4; ni++)
      bfr[ni] = *(const short8*)&sm[3 * ASZ + cb * BSZ + (wn + ni * 16 + lr) * 32 + swz];
    __builtin_amdgcn_s_setprio(1);
#pragma unroll
    for (int mi = 0; mi < MI; mi++)
#pragma unroll
      for (int ni = 0; ni < 4; ni++)
        acc[mi][ni] = mfma16(af[mi], bfr[ni], acc[mi][ni]);
    __builtin_amdgcn_s_setprio(0);

    cb = (cb == 2) ? 0 : cb + 1;
    sb = (sb == 2) ? 0 : sb + 1;
  }

  if (MODE == 1) {
#pragma unroll
    for (int mi = 0; mi < MI; mi++)
#pragma unroll
      for (int ni = 0; ni < 4; ni++)
#pragma unroll
        for (int r = 0; r < 4; r++) {
          const int i = m0 + wm + mi * 16 + lg * 4 + r;
          const int j = n0 + wn + ni * 16 + lr;
          const size_t o = (size_t)i * 1024 + j;
          outF[o] = acc[mi][ni][r] + resid[o];
        }
    return;
  }

  // ---- MODE 0 epilogue: drain in-flight wrap stages, then reuse LDS ----
  asm volatile("s_waitcnt vmcnt(0)" ::: "memory");
  __syncthreads();

  const int seg = (n0 + wn) >> 10;
  const int g8 = lane >> 3, j8 = lane & 7;
  if (seg < 2) {
    u16* epi = &sm[wid * 4608];
    const float qs = (seg == 0) ? 0.125f : 1.0f;
#pragma unroll
    for (int mi = 0; mi < 4; mi++)
#pragma unroll
      for (int ni = 0; ni < 4; ni++)
#pragma unroll
        for (int r = 0; r < 4; r++)
          epi[(mi * 16 + lg * 4 + r) * 72 + ni * 16 + lr] = f2bf(acc[mi][ni][r] * qs);
    __syncthreads();
    u16* dst = (seg == 0) ? outQ : outK;
    const int h = ((n0 + wn) & 1023) >> 6;
#pragma unroll
    for (int it = 0; it < 8; it++) {
      const int ml = it * 8 + g8;
      short8 v = *(const short8*)&epi[ml * 72 + j8 * 8];
      const int i = m0 + wm + ml;
      const int b = i >> 10, s_ = i & 1023;
      *(short8*)&dst[((size_t)(b * 16 + h) * 1024 + s_) * 64 + j8 * 8] = v;
    }
  } else {
    u16* epi = &sm[wid * 4096];
#pragma unroll
    for (int mi = 0; mi < 4; mi++)
#pragma unroll
      for (int ni = 0; ni < 4; ni++) {
        const int n = ni * 16 + lr;
        const int c2 = 4 * mi + lg;
        uint2 w;
        w.x = (unsigned)f2bf(acc[mi][ni][0]) | ((unsigned)f2bf(acc[mi][ni][1]) << 16);
        w.y = (unsigned)f2bf(acc[mi][ni][2]) | ((unsigned)f2bf(acc[mi][ni][3]) << 16);
        *(uint2*)&epi[n * 64 + ((c2 ^ (n & 15)) << 2)] = w;
      }
    __syncthreads();
    const int h = ((n0 + wn) & 1023) >> 6;
    const int b = (m0 + wm) >> 10, sbm = (m0 + wm) & 1023;
#pragma unroll
    for (int it = 0; it < 8; it++) {
      const int n = it * 8 + g8;
      uint2 w0 = *(const uint2*)&epi[n * 64 + (((2 * j8) ^ (n & 15)) << 2)];
      uint2 w1 = *(const uint2*)&epi[n * 64 + (((2 * j8 + 1) ^ (n & 15)) << 2)];
      uint4 w; w.x = w0.x; w.y = w0.y; w.z = w1.x; w.w = w1.y;
      *(uint4*)&outVt[((size_t)(b * 16 + h) * 64 + n) * 1024 + sbm + j8 * 8] = w;
    }
  }
}

// ---------------- flash attention: per (b,h,qtile=64) block, 4 waves x 16 q-rows ----
// R4 structure (62 µs proven). SWAPPED QK^T: s = mfma(K, Q) -> rows = keys,
// cols = q (lane owns q = qbase+lr). K/V LDS chunk-XOR swizzled; dbuf with one
// vmcnt(0)+s_barrier per tile; mask read directly as float4, prefetched.
__global__ __launch_bounds__(256) void flash_kernel(const u16* __restrict__ Qg,
                                                    const u16* __restrict__ Kg,
                                                    const u16* __restrict__ Vt,
                                                    const float* __restrict__ mask,
                                                    u16* __restrict__ ctx) {
  const int h = blockIdx.x, qt = blockIdx.y, b = blockIdx.z;
  const int bh = b * 16 + h;
  __shared__ u16 Ks[2][4096];       // dbuf swizzled [key][d]
  __shared__ u16 Vs[2][4096];       // dbuf swizzled [d][key]
  __shared__ u16 Ps[4][1024];       // per-wave swizzled P [16 q][64 key]
  const int t = threadIdx.x, wid = t >> 6, lane = t & 63;
  const int lr = lane & 15, lg = lane >> 4;
  const int hR = lr & 7;
  const int qbase = qt * 64 + wid * 16;

  short8 qf0, qf1;
  {
    const u16* qrow = Qg + ((size_t)bh * 1024 + qbase + lr) * 64;
    qf0 = *(const short8*)(qrow + lg * 8);
    qf1 = *(const short8*)(qrow + 32 + lg * 8);
  }
  f32x4 octx[4] = {};
  float m_ln = -1e30f, l_ln = 0.0f;

  const u16* kS0 = Kg + (size_t)bh * 65536;
  const u16* vS0 = Vt + (size_t)bh * 65536;
  const int srow = t >> 3, scb = t & 7;

  const float* mptr = mask + ((size_t)b * 1024 + qbase + lr) * 1024 + lg * 4;

  auto STAGE = [&](int nb, int kt) {
#pragma unroll
    for (int c = 0; c < 2; c++) {
      const int row = c * 32 + srow;
      const int sc = (scb ^ (row & 7)) * 8;
      gload_lds16(kS0 + (size_t)(kt * 64 + row) * 64 + sc, &Ks[nb][c * 2048 + t * 8]);
      gload_lds16(vS0 + (size_t)row * 1024 + kt * 64 + sc, &Vs[nb][c * 2048 + t * 8]);
    }
  };

  STAGE(0, 0);
  float mc[4][4];
#pragma unroll
  for (int kn = 0; kn < 4; kn++) {
    float4 v = *(const float4*)(mptr + kn * 16);
    mc[kn][0] = v.x; mc[kn][1] = v.y; mc[kn][2] = v.z; mc[kn][3] = v.w;
  }
  asm volatile("s_waitcnt vmcnt(0)" ::: "memory");
  __builtin_amdgcn_s_barrier();
  __builtin_amdgcn_sched_barrier(0);

  int cur = 0;
  for (int kt = 0; kt < 16; kt++) {
    const int ktn = (kt < 15) ? kt + 1 : 15;
    STAGE(cur ^ 1, ktn);
    float mnx[4][4];
#pragma unroll
    for (int kn = 0; kn < 4; kn++) {
      float4 v = *(const float4*)(mptr + ktn * 64 + kn * 16);
      mnx[kn][0] = v.x; mnx[kn][1] = v.y; mnx[kn][2] = v.z; mnx[kn][3] = v.w;
    }

    // ---- S = K Q^T: sv[kn][r] = score(key kn*16+lg*4+r, q=lr)
    float sv[4][4];
#pragma unroll
    for (int kn = 0; kn < 4; kn++) {
      const int R = kn * 16 + lr;
      short8 kf0 = *(const short8*)&Ks[cur][R * 64 + ((lg ^ hR) << 3)];
      short8 kf1 = *(const short8*)&Ks[cur][R * 64 + (((lg + 4) ^ hR) << 3)];
      f32x4 s = {};
      s = mfma16(kf0, qf0, s);
      s = mfma16(kf1, qf1, s);
      __builtin_amdgcn_s_setprio(0);
#pragma unroll
      for (int r = 0; r < 4; r++)
        sv[kn][r] = s[r] + fmaf(10000.f, mc[kn][r], -10000.f);
    }

    // ---- online softmax for q=lr: in-register tree + 2 shfl_xor
    float mx0 = fmaxf(fmaxf(sv[0][0], sv[0][1]), fmaxf(sv[0][2], sv[0][3]));
    float mx1 = fmaxf(fmaxf(sv[1][0], sv[1][1]), fmaxf(sv[1][2], sv[1][3]));
    float mx2 = fmaxf(fmaxf(sv[2][0], sv[2][1]), fmaxf(sv[2][2], sv[2][3]));
    float mx3 = fmaxf(fmaxf(sv[3][0], sv[3][1]), fmaxf(sv[3][2], sv[3][3]));
    float mt = fmaxf(fmaxf(mx0, mx1), fmaxf(mx2, mx3));
    mt = fmaxf(mt, __shfl_xor(mt, 16));
    mt = fmaxf(mt, __shfl_xor(mt, 32));
    const float mn = fmaxf(m_ln, mt);
    const float f = __expf(m_ln - mn);
    m_ln = mn;
    float ps = 0.0f;
#pragma unroll
    for (int kn = 0; kn < 4; kn++) {
      float p0 = __expf(sv[kn][0] - mn), p1 = __expf(sv[kn][1] - mn);
      float p2 = __expf(sv[kn][2] - mn), p3 = __expf(sv[kn][3] - mn);
      sv[kn][0] = p0; sv[kn][1] = p1; sv[kn][2] = p2; sv[kn][3] = p3;
      ps += (p0 + p1) + (p2 + p3);
    }
    ps += __shfl_xor(ps, 16);
    ps += __shfl_xor(ps, 32);
    l_ln = l_ln * f + ps;

    float fb[4];
#pragma unroll
    for (int r = 0; r < 4; r++)
      fb[r] = __shfl(f, (lane & 48) | (lg * 4 + r), 64);
#pragma unroll
    for (int g = 0; g < 4; g++)
#pragma unroll
      for (int r = 0; r < 4; r++) octx[g][r] *= fb[r];

    // ---- P -> per-wave swizzled LDS -> A-frags
    const int pswz = (lr & 7) << 1;
#pragma unroll
    for (int kn = 0; kn < 4; kn++) {
      uint2 w;
      w.x = (unsigned)f2bf(sv[kn][0]) | ((unsigned)f2bf(sv[kn][1]) << 16);
      w.y = (unsigned)f2bf(sv[kn][2]) | ((unsigned)f2bf(sv[kn][3]) << 16);
      *(uint2*)&Ps[wid][lr * 64 + (((kn * 4 + lg) ^ pswz) << 2)] = w;
    }
    short8 pa0 = *(const short8*)&Ps[wid][lr * 64 + (((2 * lg) ^ pswz) << 2)];
    short8 pa1 = *(const short8*)&Ps[wid][lr * 64 + (((8 + 2 * lg) ^ pswz) << 2)];

    // ---- PV
    __builtin_amdgcn_s_setprio(1);
#pragma unroll
    for (int g = 0; g < 4; g++) {
      const int R = g * 16 + lr;
      short8 vf0 = *(const short8*)&Vs[cur][R * 64 + ((lg ^ hR) << 3)];
      short8 vf1 = *(const short8*)&Vs[cur][R * 64 + (((lg + 4) ^ hR) << 3)];
      octx[g] = mfma16(pa0, vf0, octx[g]);
      octx[g] = mfma16(pa1, vf1, octx[g]);
    }
    __builtin_amdgcn_s_setprio(0);

    asm volatile("s_waitcnt vmcnt(0)" ::: "memory");
    __builtin_amdgcn_s_barrier();
    __builtin_amdgcn_sched_barrier(0);
    cur ^= 1;
#pragma unroll
    for (int kn = 0; kn < 4; kn++)
#pragma unroll
      for (int r = 0; r < 4; r++) mc[kn][r] = mnx[kn][r];
  }

  float lb[4];
#pragma unroll
  for (int r = 0; r < 4; r++)
    lb[r] = __shfl(l_ln, (lane & 48) | (lg * 4 + r), 64);
#pragma unroll
  for (int g = 0; g < 4; g++)
#pragma unroll
    for (int r = 0; r < 4; r++) {
      const int qr = qbase + lg * 4 + r;
      ctx[((size_t)b * 1024 + qr) * 1024 + h * 64 + g * 16 + lr] = f2bf(octx[g][r] / lb[r]);
    }
}

extern "C" void kernel_launch(void* const* d_in, const int* in_sizes, int n_in,
                              void* d_out, int out_size, void* d_ws, size_t ws_size,
                              hipStream_t stream) {
  const float* x     = (const float*)d_in[0];
  const float* mask  = (const float*)d_in[2];
  const float* wq    = (const float*)d_in[3];
  const float* wk    = (const float*)d_in[4];
  const float* wv    = (const float*)d_in[5];
  const float* wo    = (const float*)d_in[6];
  const float* gamma = (const float*)d_in[7];
  const float* beta  = (const float*)d_in[8];
  float* out = (float*)d_out;

  char* ws = (char*)d_ws;
  u16* normed = (u16*)(ws);
  u16* wcat   = (u16*)(ws + (8ull << 20));
  u16* Qg     = (u16*)(ws + (16ull << 20));
  u16* Kg     = (u16*)(ws + (24ull << 20));
  u16* Vtg    = (u16*)(ws + (32ull << 20));
  u16* ctx    = (u16*)(ws + (40ull << 20));
  u16* wo_bf  = wcat + 3072ull * 1024;

  // LN (blocks 0..4095) + weight cvt (blocks 4096..8191) fused
  prep_kernel<<<8192, 256, 0, stream>>>(x, gamma, beta, normed, wq, wk, wv, wo, wcat);
  // QKV: M=4096, N=3072, 128x128 tiles
  gemm_bt<0><<<dim3(24, 32), 256, 0, stream>>>(normed, wcat, Qg, Kg, Vtg, nullptr, nullptr);
  // attention: grid x=h (16 heads share per-b mask slice in L2), y=qtile, z=b
  flash_kernel<<<dim3(16, 16, 4), 256, 0, stream>>>(Qg, Kg, Vtg, mask, ctx);
  // WO + residual: M=4096, N=1024, 64x128 tiles
  gemm_bt<1><<<dim3(8, 64), 256, 0, stream>>>(ctx, wo_bf, nullptr, nullptr, nullptr, out, x);
}